// Round 3
// baseline (611.647 us; speedup 1.0000x reference)
//
#include <hip/hip_runtime.h>

#define NU_ 100000
#define NI_ 50000
#define D_  128
#define C_  5
#define V_  200000
#define E_  200000
#define L_  10

typedef __bf16 bf16x8 __attribute__((ext_vector_type(8)));
typedef unsigned short u16;
typedef u16 u16x8 __attribute__((ext_vector_type(8)));
typedef float f32x4 __attribute__((ext_vector_type(4)));

// ws layout (bytes): [0..4) loss acc; [256..) swizzled bf16 weights (196 KB);
// [256K..) embB = V*D bf16 (51.2 MB); [EMB+51.2M..) thB = E*D bf16 (51.2 MB).
#define W1R_OFF 0
#define W2R_OFF 32768
#define W1T_OFF 49152
#define W2T_OFF 81920
#define WTOT    98304
#define EMB_BYTE_OFF (256 * 1024)
#define EMB_ELEMS    (V_ * D_)
#define TH_BYTE_OFF  (EMB_BYTE_OFF + EMB_ELEMS * 2)
#define TH_BYTES     ((size_t)E_ * D_ * 2)

__device__ __forceinline__ u16 f2bf(float x) {
    union { float f; unsigned int u; } v; v.f = x;
    unsigned int u = v.u;
    return (u16)((u + 0x7FFFu + ((u >> 16) & 1u)) >> 16);
}
__device__ __forceinline__ float bfhi(unsigned int u) {
    union { unsigned int u; float f; } v; v.u = u & 0xFFFF0000u; return v.f;
}
__device__ __forceinline__ float bflo(unsigned int u) {
    union { unsigned int u; float f; } v; v.u = u << 16; return v.f;
}

// weights f32 -> bf16, MFMA-B-fragment swizzle: dest[((k>>3)*128+n)*8+(k&7)] = W[k*128+n]
__global__ void prep_kernel(const float* __restrict__ w1r, const float* __restrict__ w2r,
                            const float* __restrict__ w1t, const float* __restrict__ w2t,
                            u16* __restrict__ wbuf, float* __restrict__ loss_acc) {
    int idx = blockIdx.x * blockDim.x + threadIdx.x;
    if (idx == 0) *loss_acc = 0.f;
    if (idx >= WTOT) return;
    const float* src; int base;
    if (idx < W2R_OFF)      { src = w1r; base = W1R_OFF; }
    else if (idx < W1T_OFF) { src = w2r; base = W2R_OFF; }
    else if (idx < W2T_OFF) { src = w1t; base = W1T_OFF; }
    else                    { src = w2t; base = W2T_OFF; }
    int local = idx - base;
    int j = local & 7;
    int g = local >> 3;
    int n = g & 127;
    int kq = g >> 7;
    wbuf[idx] = f2bf(src[(kq * 8 + j) * 128 + n]);
}

// bulk f32 -> bf16 convert, 8 elems/thread (used for emb only: 51.2 MB)
__global__ void cvt_kernel(const float* __restrict__ src, u16* __restrict__ dst, int n8) {
    int i = blockIdx.x * blockDim.x + threadIdx.x;
    if (i >= n8) return;
    float4 a = *(const float4*)(src + (size_t)i * 8);
    float4 b = *(const float4*)(src + (size_t)i * 8 + 4);
    u16x8 v;
    v[0] = f2bf(a.x); v[1] = f2bf(a.y); v[2] = f2bf(a.z); v[3] = f2bf(a.w);
    v[4] = f2bf(b.x); v[5] = f2bf(b.y); v[6] = f2bf(b.z); v[7] = f2bf(b.w);
    *(u16x8*)(dst + (size_t)i * 8) = v;
}

// Stage 16 edges x 128 dims (one half of the concat input) into LDS A-frag layout.
__device__ __forceinline__ void stage_half(const float* __restrict__ row, int lane, u16* buf) {
    int m = lane >> 2, q = lane & 3;
    const float* seg = row + q * 32;
#pragma unroll
    for (int i = 0; i < 4; i++) {
        float4 a = *(const float4*)(seg + i * 8);
        float4 b = *(const float4*)(seg + i * 8 + 4);
        u16x8 v;
        v[0] = f2bf(a.x); v[1] = f2bf(a.y); v[2] = f2bf(a.z); v[3] = f2bf(a.w);
        v[4] = f2bf(b.x); v[5] = f2bf(b.y); v[6] = f2bf(b.z); v[7] = f2bf(b.w);
        *(u16x8*)(buf + ((q * 4 + i) * 16 + m) * 8) = v;
    }
}

// 16x128 tile GEMM over K = KT*32; A frags from LDS, B frags from swizzled weights.
template <int KT>
__device__ __forceinline__ void gemm_tile(const u16* aLDS, const u16* __restrict__ Wg,
                                          int lq, int ln, f32x4 acc[8]) {
#pragma unroll
    for (int kt = 0; kt < KT; kt++) {
        bf16x8 af = *(const bf16x8*)(aLDS + ((kt * 4 + lq) * 16 + ln) * 8);
#pragma unroll
        for (int nt = 0; nt < 8; nt++) {
            bf16x8 bfv = *(const bf16x8*)(Wg + (size_t)((kt * 4 + lq) * 128 + nt * 16 + ln) * 8);
            acc[nt] = __builtin_amdgcn_mfma_f32_16x16x32_bf16(af, bfv, acc[nt], 0, 0, 0);
        }
    }
}

// relu(acc) -> LDS bf16 A-frag layout (next GEMM's A).
__device__ __forceinline__ void store_h_relu(const f32x4 acc[8], u16* buf, int lq, int ln) {
#pragma unroll
    for (int nt = 0; nt < 8; nt++)
#pragma unroll
        for (int reg = 0; reg < 4; reg++) {
            float h = fmaxf(acc[nt][reg], 0.f);
            int dcol = nt * 16 + ln;
            int r = lq * 4 + reg;
            buf[((dcol >> 3) * 16 + r) * 8 + (dcol & 7)] = f2bf(h);
        }
}

// One 2-layer MLP over concat([u[src],i[dst]]) staged as two K=128 halves.
__device__ __forceinline__ void mlp(const float* __restrict__ uF, const float* __restrict__ iF,
                                    const int* __restrict__ srcI, const int* __restrict__ dstI,
                                    int ebase, int lane, int lq, int ln,
                                    const u16* __restrict__ w1, const u16* __restrict__ w2,
                                    u16* bufA, u16* bufB, f32x4 acc[8]) {
    int e = ebase + (lane >> 2);
    int su = srcI[e], sd = dstI[e];
    f32x4 h1[8];
#pragma unroll
    for (int nt = 0; nt < 8; nt++) h1[nt] = (f32x4){0.f, 0.f, 0.f, 0.f};

    stage_half(uF + (size_t)su * D_, lane, bufA);
    __syncthreads();
    gemm_tile<4>(bufA, w1, lq, ln, h1);               // K 0..127
    __syncthreads();
    stage_half(iF + (size_t)sd * D_, lane, bufA);
    __syncthreads();
    gemm_tile<4>(bufA, w1 + 16384, lq, ln, h1);       // K 128..255
    store_h_relu(h1, bufB, lq, ln);
    __syncthreads();
    gemm_tile<4>(bufB, w2, lq, ln, acc);
}

__device__ __forceinline__ float softplus_(float x) {
    return fmaxf(x, 0.f) + log1pf(expf(-fabsf(x)));
}

// ============================================================================
// SPLIT PATH: mlp_kernel (MFMA-heavy, 84 VGPR, 3 waves/EU) writes th as bf16;
// review_kernel (gather-heavy, <=64 VGPR, 8 waves/EU) reads it back.
// Rationale: old fused kernel was latency-bound (Mfma 4.4%, VALU 18%, HBM 24%,
// occ 30%) -- the gather phase inherited the MLP's register-capped occupancy.
// ============================================================================

__global__ __launch_bounds__(256, 3) void mlp_kernel(
    const float* __restrict__ urf, const float* __restrict__ irf,
    const float* __restrict__ utf, const float* __restrict__ itf,
    const float* __restrict__ wp,
    const int* __restrict__ srcI, const int* __restrict__ dstI,
    const u16* __restrict__ wbuf, float* __restrict__ out,
    u16* __restrict__ thB) {
    __shared__ u16 smem[4 * 4096];        // per wave: bufA 2048 + bufB 2048 u16 (8 KB)
    const int tid = threadIdx.x;
    const int w = tid >> 6;
    const int lane = tid & 63;
    const int lq = lane >> 4;
    const int ln = lane & 15;
    u16* bufA = smem + w * 4096;
    u16* bufB = bufA + 2048;
    const int ebase = blockIdx.x * 64 + w * 16;

    // ---------- rating path ----------
    f32x4 rh[8];
#pragma unroll
    for (int nt = 0; nt < 8; nt++) rh[nt] = (f32x4){0.f, 0.f, 0.f, 0.f};
    mlp(urf, irf, srcI, dstI, ebase, lane, lq, ln,
        wbuf + W1R_OFF, wbuf + W2R_OFF, bufA, bufB, rh);

    // ---------- pr = rh @ wp ----------
    {
        float pp[4][5];
#pragma unroll
        for (int r = 0; r < 4; r++)
#pragma unroll
            for (int c = 0; c < 5; c++) pp[r][c] = 0.f;
#pragma unroll
        for (int nt = 0; nt < 8; nt++) {
            int d = nt * 16 + ln;
            float wpc[5];
#pragma unroll
            for (int c = 0; c < 5; c++) wpc[c] = wp[d * 5 + c];
#pragma unroll
            for (int reg = 0; reg < 4; reg++)
#pragma unroll
                for (int c = 0; c < 5; c++) pp[reg][c] += rh[nt][reg] * wpc[c];
        }
#pragma unroll
        for (int off = 1; off < 16; off <<= 1)
#pragma unroll
            for (int reg = 0; reg < 4; reg++)
#pragma unroll
                for (int c = 0; c < 5; c++)
                    pp[reg][c] += __shfl_xor(pp[reg][c], off, 64);
        if (ln == 0) {
#pragma unroll
            for (int reg = 0; reg < 4; reg++) {
                int e = ebase + lq * 4 + reg;
#pragma unroll
                for (int c = 0; c < 5; c++) out[(size_t)e * 5 + c] = pp[reg][c];
            }
        }
    }

    // ---------- topic path (residual) ----------
    __syncthreads();
    f32x4 th[8];
#pragma unroll
    for (int nt = 0; nt < 8; nt++) th[nt] = rh[nt];
    mlp(utf, itf, srcI, dstI, ebase, lane, lq, ln,
        wbuf + W1T_OFF, wbuf + W2T_OFF, bufA, bufB, th);

    // th -> LDS f32 plain layout (16 rows x 128 cols over bufA+bufB)
    __syncthreads();
    float* thb = (float*)bufA;
#pragma unroll
    for (int nt = 0; nt < 8; nt++)
#pragma unroll
        for (int reg = 0; reg < 4; reg++)
            thb[(lq * 4 + reg) * 128 + nt * 16 + ln] = th[nt][reg];
    __syncthreads();

    // coalesced bf16 writeout: per row, 64 lanes each pack 2 cols -> 256 B store
#pragma unroll
    for (int m = 0; m < 16; m++) {
        float2 ab = *(const float2*)(thb + m * 128 + lane * 2);
        unsigned pk = (unsigned)f2bf(ab.x) | ((unsigned)f2bf(ab.y) << 16);
        ((unsigned*)(thB + (size_t)(ebase + m) * D_))[lane] = pk;
    }
}

// One edge per 16-lane group; indices preloaded coalesced + shfl-broadcast,
// removing the dependent global index load from the gather chain.
// launch_bounds (256,8): cap at 64 VGPR -> 8 waves/SIMD for latency hiding.
__global__ __launch_bounds__(256, 8) void review_kernel(
    const u16* __restrict__ thB, const u16* __restrict__ embB,
    const int* __restrict__ sidI, const int* __restrict__ nsidI,
    float* __restrict__ loss_acc) {
    __shared__ float red[4];
    const int tid = threadIdx.x;
    const int lane = tid & 63;
    const int gl = tid & 15;
    const int e = blockIdx.x * 16 + (tid >> 4);

    int ip = 0, in_ = 0;
    if (gl < L_) { ip = sidI[e * L_ + gl]; in_ = nsidI[e * L_ + gl]; }

    float th8[8];
    {
        union { u16x8 v; unsigned int u[4]; } tu;
        tu.v = *(const u16x8*)(thB + (size_t)e * D_ + gl * 8);
#pragma unroll
        for (int k = 0; k < 4; k++) {
            th8[2 * k]     = bflo(tu.u[k]);
            th8[2 * k + 1] = bfhi(tu.u[k]);
        }
    }

    float ps = 0.f, ns = 0.f;
    float pc = (gl < L_ && ip > 0) ? 1.f : 0.f;
    float nc = (gl < L_ && in_ > 0) ? 1.f : 0.f;

#pragma unroll
    for (int i = 0; i < L_; i++) {
        int s = __shfl(ip, i, 16);
        union { u16x8 v; unsigned int u[4]; } cv;
        cv.v = *(const u16x8*)(embB + (size_t)s * D_ + gl * 8);
        int t = __shfl(in_, i, 16);
        union { u16x8 v; unsigned int u[4]; } nv;
        nv.v = *(const u16x8*)(embB + (size_t)t * D_ + gl * 8);
#pragma unroll
        for (int k = 0; k < 4; k++) {
            ps = fmaf(th8[2 * k],     bflo(cv.u[k]), ps);
            ps = fmaf(th8[2 * k + 1], bfhi(cv.u[k]), ps);
        }
#pragma unroll
        for (int k = 0; k < 4; k++) {
            ns = fmaf(th8[2 * k],     bflo(nv.u[k]), ns);
            ns = fmaf(th8[2 * k + 1], bfhi(nv.u[k]), ns);
        }
    }

#pragma unroll
    for (int off = 1; off < 16; off <<= 1) {
        ps += __shfl_xor(ps, off, 64);
        ns += __shfl_xor(ns, off, 64);
        pc += __shfl_xor(pc, off, 64);
        nc += __shfl_xor(nc, off, 64);
    }
    float val = softplus_(ns / (nc + 1e-9f) - ps / (pc + 1e-9f));
    float wl = (gl == 0) ? val : 0.f;
    wl += __shfl_xor(wl, 16, 64);
    wl += __shfl_xor(wl, 32, 64);
    if (lane == 0) red[tid >> 6] = wl;
    __syncthreads();
    if (tid == 0) atomicAdd(loss_acc, red[0] + red[1] + red[2] + red[3]);
}

// ============================================================================
// FALLBACK: original fused kernel (used only if ws too small for th buffer)
// ============================================================================
template <bool EB>
__global__ __launch_bounds__(256, 3) void fused_kernel(
    const float* __restrict__ urf, const float* __restrict__ irf,
    const float* __restrict__ utf, const float* __restrict__ itf,
    const float* __restrict__ wp, const float* __restrict__ emb,
    const u16* __restrict__ embB,
    const int* __restrict__ srcI, const int* __restrict__ dstI,
    const int* __restrict__ sidI, const int* __restrict__ nsidI,
    const u16* __restrict__ wbuf, float* __restrict__ loss_acc,
    float* __restrict__ out) {
    __shared__ u16 smem[4 * 4096];
    const int tid = threadIdx.x;
    const int w = tid >> 6;
    const int lane = tid & 63;
    const int lq = lane >> 4;
    const int ln = lane & 15;
    u16* bufA = smem + w * 4096;
    u16* bufB = bufA + 2048;
    const int ebase = blockIdx.x * 64 + w * 16;

    f32x4 rh[8];
#pragma unroll
    for (int nt = 0; nt < 8; nt++) rh[nt] = (f32x4){0.f, 0.f, 0.f, 0.f};
    mlp(urf, irf, srcI, dstI, ebase, lane, lq, ln,
        wbuf + W1R_OFF, wbuf + W2R_OFF, bufA, bufB, rh);

    {
        float pp[4][5];
#pragma unroll
        for (int r = 0; r < 4; r++)
#pragma unroll
            for (int c = 0; c < 5; c++) pp[r][c] = 0.f;
#pragma unroll
        for (int nt = 0; nt < 8; nt++) {
            int d = nt * 16 + ln;
            float wpc[5];
#pragma unroll
            for (int c = 0; c < 5; c++) wpc[c] = wp[d * 5 + c];
#pragma unroll
            for (int reg = 0; reg < 4; reg++)
#pragma unroll
                for (int c = 0; c < 5; c++) pp[reg][c] += rh[nt][reg] * wpc[c];
        }
#pragma unroll
        for (int off = 1; off < 16; off <<= 1)
#pragma unroll
            for (int reg = 0; reg < 4; reg++)
#pragma unroll
                for (int c = 0; c < 5; c++)
                    pp[reg][c] += __shfl_xor(pp[reg][c], off, 64);
        if (ln == 0) {
#pragma unroll
            for (int reg = 0; reg < 4; reg++) {
                int e = ebase + lq * 4 + reg;
#pragma unroll
                for (int c = 0; c < 5; c++) out[(size_t)e * 5 + c] = pp[reg][c];
            }
        }
    }

    __syncthreads();
    f32x4 th[8];
#pragma unroll
    for (int nt = 0; nt < 8; nt++) th[nt] = rh[nt];
    mlp(utf, itf, srcI, dstI, ebase, lane, lq, ln,
        wbuf + W1T_OFF, wbuf + W2T_OFF, bufA, bufB, th);

    __syncthreads();
    float* thb = (float*)bufA;
    if constexpr (EB) {
#pragma unroll
        for (int nt = 0; nt < 8; nt++)
#pragma unroll
            for (int reg = 0; reg < 4; reg++) {
                int col = nt * 16 + ln;
                thb[((lq * 4 + reg) * 16 + (col >> 3)) * 8 + (col & 7)] = th[nt][reg];
            }
    } else {
#pragma unroll
        for (int nt = 0; nt < 8; nt++)
#pragma unroll
            for (int reg = 0; reg < 4; reg++)
                thb[(lq * 4 + reg) * 128 + nt * 16 + ln] = th[nt][reg];
    }
    __syncthreads();

    float wave_loss = 0.f;
    if constexpr (EB) {
        const int g = lane >> 4, gl = lane & 15;
        for (int it = 0; it < 4; it++) {
            int m = it * 4 + g;
            int e = ebase + m;
            float th8[8];
            *(f32x4*)th8       = *(const f32x4*)(thb + (m * 16 + gl) * 8);
            *(f32x4*)(th8 + 4) = *(const f32x4*)(thb + (m * 16 + gl) * 8 + 4);
            float ps = 0.f, ns = 0.f;
            int pcnt = 0, ncnt = 0;
#pragma unroll
            for (int i = 0; i < L_; i++) {
                int s = sidI[e * L_ + i];
                pcnt += (s > 0) ? 1 : 0;
                union { u16x8 v; unsigned int u[4]; } cv;
                cv.v = *(const u16x8*)(embB + (size_t)s * D_ + gl * 8);
#pragma unroll
                for (int k = 0; k < 4; k++) {
                    ps = fmaf(th8[2 * k],     bflo(cv.u[k]), ps);
                    ps = fmaf(th8[2 * k + 1], bfhi(cv.u[k]), ps);
                }
            }
#pragma unroll
            for (int i = 0; i < L_; i++) {
                int s = nsidI[e * L_ + i];
                ncnt += (s > 0) ? 1 : 0;
                union { u16x8 v; unsigned int u[4]; } cv;
                cv.v = *(const u16x8*)(embB + (size_t)s * D_ + gl * 8);
#pragma unroll
                for (int k = 0; k < 4; k++) {
                    ns = fmaf(th8[2 * k],     bflo(cv.u[k]), ns);
                    ns = fmaf(th8[2 * k + 1], bfhi(cv.u[k]), ns);
                }
            }
#pragma unroll
            for (int off = 1; off < 16; off <<= 1) {
                ps += __shfl_xor(ps, off, 64);
                ns += __shfl_xor(ns, off, 64);
            }
            if (gl == 0) {
                ps /= ((float)pcnt + 1e-9f);
                ns /= ((float)ncnt + 1e-9f);
                wave_loss += softplus_(ns - ps);
            }
        }
        wave_loss += __shfl_xor(wave_loss, 16, 64);
        wave_loss += __shfl_xor(wave_loss, 32, 64);
    } else {
        const int h = lane >> 5, hl = lane & 31;
        for (int mp = 0; mp < 16; mp += 2) {
            int m = mp + h;
            int e = ebase + m;
            float4 t4 = *(const float4*)(thb + m * 128 + hl * 4);
            float ps = 0.f, ns = 0.f;
            int pcnt = 0, ncnt = 0;
#pragma unroll
            for (int i = 0; i < L_; i++) {
                int s = sidI[e * L_ + i];
                pcnt += (s > 0) ? 1 : 0;
                float4 ev = *(const float4*)(emb + (size_t)s * D_ + hl * 4);
                ps += t4.x * ev.x + t4.y * ev.y + t4.z * ev.z + t4.w * ev.w;
            }
#pragma unroll
            for (int i = 0; i < L_; i++) {
                int s = nsidI[e * L_ + i];
                ncnt += (s > 0) ? 1 : 0;
                float4 ev = *(const float4*)(emb + (size_t)s * D_ + hl * 4);
                ns += t4.x * ev.x + t4.y * ev.y + t4.z * ev.z + t4.w * ev.w;
            }
#pragma unroll
            for (int off = 1; off < 32; off <<= 1) {
                ps += __shfl_xor(ps, off, 64);
                ns += __shfl_xor(ns, off, 64);
            }
            if (hl == 0) {
                ps /= ((float)pcnt + 1e-9f);
                ns /= ((float)ncnt + 1e-9f);
                wave_loss += softplus_(ns - ps);
            }
        }
        wave_loss += __shfl_xor(wave_loss, 32, 64);
    }
    if (lane == 0) atomicAdd(loss_acc, wave_loss);
}

__global__ void finish_kernel(const float* __restrict__ loss_acc, float* __restrict__ out) {
    float v = loss_acc[0] * (1.0f / (float)E_);
    out[(size_t)E_ * C_]     = v;
    out[(size_t)E_ * C_ + 1] = v;
}

extern "C" void kernel_launch(void* const* d_in, const int* in_sizes, int n_in,
                              void* d_out, int out_size, void* d_ws, size_t ws_size,
                              hipStream_t stream) {
    const float* urf = (const float*)d_in[0];
    const float* irf = (const float*)d_in[1];
    const float* utf = (const float*)d_in[2];
    const float* itf = (const float*)d_in[3];
    const float* w1r = (const float*)d_in[4];
    const float* w2r = (const float*)d_in[5];
    const float* w1t = (const float*)d_in[6];
    const float* w2t = (const float*)d_in[7];
    const float* wp  = (const float*)d_in[8];
    const float* emb = (const float*)d_in[9];
    const int* srcI  = (const int*)d_in[10];
    const int* dstI  = (const int*)d_in[11];
    const int* sidI  = (const int*)d_in[12];
    const int* nsidI = (const int*)d_in[13];
    float* out = (float*)d_out;

    float* loss_acc = (float*)d_ws;
    u16* wbuf = (u16*)((char*)d_ws + 256);
    u16* embB = (u16*)((char*)d_ws + EMB_BYTE_OFF);
    u16* thB  = (u16*)((char*)d_ws + TH_BYTE_OFF);

    bool eb = ws_size >= (size_t)EMB_BYTE_OFF + (size_t)EMB_ELEMS * 2;
    bool tb = ws_size >= (size_t)TH_BYTE_OFF + TH_BYTES;

    prep_kernel<<<(WTOT + 255) / 256, 256, 0, stream>>>(w1r, w2r, w1t, w2t, wbuf, loss_acc);
    if (eb)
        cvt_kernel<<<(EMB_ELEMS / 8 + 255) / 256, 256, 0, stream>>>(emb, embB, EMB_ELEMS / 8);

    if (tb) {
        mlp_kernel<<<E_ / 64, 256, 0, stream>>>(
            urf, irf, utf, itf, wp, srcI, dstI, wbuf, out, thB);
        review_kernel<<<E_ / 16, 256, 0, stream>>>(
            thB, embB, sidI, nsidI, loss_acc);
    } else if (eb) {
        fused_kernel<true><<<E_ / 64, 256, 0, stream>>>(
            urf, irf, utf, itf, wp, emb, embB,
            srcI, dstI, sidI, nsidI, wbuf, loss_acc, out);
    } else {
        fused_kernel<false><<<E_ / 64, 256, 0, stream>>>(
            urf, irf, utf, itf, wp, emb, embB,
            srcI, dstI, sidI, nsidI, wbuf, loss_acc, out);
    }

    finish_kernel<<<1, 1, 0, stream>>>(loss_acc, out);
}

// Round 4
// 600.492 us; speedup vs baseline: 1.0186x; 1.0186x over previous
//
#include <hip/hip_runtime.h>

#define NU_ 100000
#define NI_ 50000
#define D_  128
#define C_  5
#define V_  200000
#define E_  200000
#define L_  10

typedef __bf16 bf16x8 __attribute__((ext_vector_type(8)));
typedef unsigned short u16;
typedef u16 u16x8 __attribute__((ext_vector_type(8)));
typedef float f32x4 __attribute__((ext_vector_type(4)));

// ws layout (bytes): [0..4) loss acc; [256..) swizzled bf16 weights (196 KB);
// [256K..) embF8 = V*D fp8 (25.6 MB); then thB = E*D bf16 (51.2 MB).
#define W1R_OFF 0
#define W2R_OFF 32768
#define W1T_OFF 49152
#define W2T_OFF 81920
#define WTOT    98304
#define EMB_BYTE_OFF (256 * 1024)
#define EMB_ELEMS    (V_ * D_)
#define TH_BYTE_OFF  (EMB_BYTE_OFF + EMB_ELEMS)     /* fp8: 1 B/elem */
#define TH_BYTES     ((size_t)E_ * D_ * 2)

__device__ __forceinline__ u16 f2bf(float x) {
    union { float f; unsigned int u; } v; v.f = x;
    unsigned int u = v.u;
    return (u16)((u + 0x7FFFu + ((u >> 16) & 1u)) >> 16);
}
__device__ __forceinline__ float bfhi(unsigned int u) {
    union { unsigned int u; float f; } v; v.u = u & 0xFFFF0000u; return v.f;
}
__device__ __forceinline__ float bflo(unsigned int u) {
    union { unsigned int u; float f; } v; v.u = u << 16; return v.f;
}

// f32 -> fp8 e4m3 (OCP), RNE. Denorm range [0,2^-6) snapped to {0, 2^-6}
// (decode flushes denorms anyway); emb ~ N(0,1) so range clamp is safety only.
__device__ __forceinline__ unsigned f2fp8(float x) {
    union { float f; unsigned u; } v; v.f = x;
    unsigned s = (v.u >> 24) & 0x80u;
    float ax = fabsf(x);
    if (ax < 0.0078125f) return s;            // < 2^-7 -> +/-0
    if (ax < 0.015625f)  return s | 0x08u;    // -> min normal 2^-6
    if (ax > 448.f)      return s | 0x7Eu;    // clamp to max finite
    unsigned u = v.u & 0x7FFFFFFFu;
    unsigned r = u + 0x7FFFFu + ((u >> 20) & 1u);  // RNE at mantissa bit 20
    unsigned c = (r >> 20) - 960u;                 // ((e-120)<<3) | m3
    if (c > 0x7Eu) c = 0x7Eu;
    return s | c;
}
// fp8 e4m3 -> f32: place payload at exp/mant, scale by 2^120. Denorms -> ~0.
__device__ __forceinline__ float fp8dec(unsigned b) {
    unsigned t = ((b & 0x80u) << 24) | ((b & 0x7Fu) << 20);
    union { unsigned u; float f; } v; v.u = t;
    return v.f * 0x1.0p+120f;
}

// Wave-private LDS fence: all bufA/bufB/bufC are PER-WAVE, so a block-wide
// __syncthreads() is overkill -- lockstep wave64 + lgkmcnt(0) guarantees
// cross-lane LDS visibility. "memory" clobber orders the ds ops around it.
__device__ __forceinline__ void lds_fence() {
    asm volatile("s_waitcnt lgkmcnt(0)" ::: "memory");
}

// weights f32 -> bf16, MFMA-B-fragment swizzle: dest[((k>>3)*128+n)*8+(k&7)] = W[k*128+n]
__global__ void prep_kernel(const float* __restrict__ w1r, const float* __restrict__ w2r,
                            const float* __restrict__ w1t, const float* __restrict__ w2t,
                            u16* __restrict__ wbuf, float* __restrict__ loss_acc) {
    int idx = blockIdx.x * blockDim.x + threadIdx.x;
    if (idx == 0) *loss_acc = 0.f;
    if (idx >= WTOT) return;
    const float* src; int base;
    if (idx < W2R_OFF)      { src = w1r; base = W1R_OFF; }
    else if (idx < W1T_OFF) { src = w2r; base = W2R_OFF; }
    else if (idx < W2T_OFF) { src = w1t; base = W1T_OFF; }
    else                    { src = w2t; base = W2T_OFF; }
    int local = idx - base;
    int j = local & 7;
    int g = local >> 3;
    int n = g & 127;
    int kq = g >> 7;
    wbuf[idx] = f2bf(src[(kq * 8 + j) * 128 + n]);
}

// bulk f32 -> fp8 convert, 8 elems/thread (emb only: 200 MB -> 25.6 MB)
__global__ void cvt8_kernel(const float* __restrict__ src, unsigned char* __restrict__ dst, int n8) {
    int i = blockIdx.x * blockDim.x + threadIdx.x;
    if (i >= n8) return;
    float4 a = *(const float4*)(src + (size_t)i * 8);
    float4 b = *(const float4*)(src + (size_t)i * 8 + 4);
    uint2 v;
    v.x = f2fp8(a.x) | (f2fp8(a.y) << 8) | (f2fp8(a.z) << 16) | (f2fp8(a.w) << 24);
    v.y = f2fp8(b.x) | (f2fp8(b.y) << 8) | (f2fp8(b.z) << 16) | (f2fp8(b.w) << 24);
    *(uint2*)(dst + (size_t)i * 8) = v;
}

// Stage 16 edges x 128 dims (one half of the concat input) into LDS A-frag layout.
__device__ __forceinline__ void stage_half(const float* __restrict__ row, int lane, u16* buf) {
    int m = lane >> 2, q = lane & 3;
    const float* seg = row + q * 32;
#pragma unroll
    for (int i = 0; i < 4; i++) {
        float4 a = *(const float4*)(seg + i * 8);
        float4 b = *(const float4*)(seg + i * 8 + 4);
        u16x8 v;
        v[0] = f2bf(a.x); v[1] = f2bf(a.y); v[2] = f2bf(a.z); v[3] = f2bf(a.w);
        v[4] = f2bf(b.x); v[5] = f2bf(b.y); v[6] = f2bf(b.z); v[7] = f2bf(b.w);
        *(u16x8*)(buf + ((q * 4 + i) * 16 + m) * 8) = v;
    }
}

// 16x128 tile GEMM over K = KT*32; A frags from LDS, B frags from swizzled weights.
template <int KT>
__device__ __forceinline__ void gemm_tile(const u16* aLDS, const u16* __restrict__ Wg,
                                          int lq, int ln, f32x4 acc[8]) {
#pragma unroll
    for (int kt = 0; kt < KT; kt++) {
        bf16x8 af = *(const bf16x8*)(aLDS + ((kt * 4 + lq) * 16 + ln) * 8);
#pragma unroll
        for (int nt = 0; nt < 8; nt++) {
            bf16x8 bfv = *(const bf16x8*)(Wg + (size_t)((kt * 4 + lq) * 128 + nt * 16 + ln) * 8);
            acc[nt] = __builtin_amdgcn_mfma_f32_16x16x32_bf16(af, bfv, acc[nt], 0, 0, 0);
        }
    }
}

// relu(acc) -> LDS bf16 A-frag layout (next GEMM's A).
__device__ __forceinline__ void store_h_relu(const f32x4 acc[8], u16* buf, int lq, int ln) {
#pragma unroll
    for (int nt = 0; nt < 8; nt++)
#pragma unroll
        for (int reg = 0; reg < 4; reg++) {
            float h = fmaxf(acc[nt][reg], 0.f);
            int dcol = nt * 16 + ln;
            int r = lq * 4 + reg;
            buf[((dcol >> 3) * 16 + r) * 8 + (dcol & 7)] = f2bf(h);
        }
}

// One 2-layer MLP. u-half and i-half staged into SEPARATE buffers so both
// row-gathers are in flight together; wave-private fences only (no barriers).
__device__ __forceinline__ void mlp2(const float* __restrict__ uRow, const float* __restrict__ iRow,
                                     int lane, int lq, int ln,
                                     const u16* __restrict__ w1, const u16* __restrict__ w2,
                                     u16* bufA, u16* bufC, u16* bufB, f32x4 acc[8]) {
    f32x4 h1[8];
#pragma unroll
    for (int nt = 0; nt < 8; nt++) h1[nt] = (f32x4){0.f, 0.f, 0.f, 0.f};
    stage_half(uRow, lane, bufA);
    stage_half(iRow, lane, bufC);
    lds_fence();
    gemm_tile<4>(bufA, w1, lq, ln, h1);               // K 0..127
    gemm_tile<4>(bufC, w1 + 16384, lq, ln, h1);       // K 128..255
    store_h_relu(h1, bufB, lq, ln);
    lds_fence();
    gemm_tile<4>(bufB, w2, lq, ln, acc);
}

__device__ __forceinline__ float softplus_(float x) {
    return fmaxf(x, 0.f) + log1pf(expf(-fabsf(x)));
}

// ============================================================================
// SPLIT PATH: mlp_kernel (MFMA, 84 VGPR, 3 waves/EU, zero block barriers)
// writes th bf16; review_kernel (gather, 8 waves/EU) reads fp8 emb.
// ============================================================================

__global__ __launch_bounds__(256, 3) void mlp_kernel(
    const float* __restrict__ urf, const float* __restrict__ irf,
    const float* __restrict__ utf, const float* __restrict__ itf,
    const float* __restrict__ wp,
    const int* __restrict__ srcI, const int* __restrict__ dstI,
    const u16* __restrict__ wbuf, float* __restrict__ out,
    u16* __restrict__ thB) {
    // per wave: bufA 2048 + bufC 2048 + bufB 2048 u16 (12 KB); 48 KB/block
    __shared__ u16 smem[4 * 6144];
    const int tid = threadIdx.x;
    const int w = tid >> 6;
    const int lane = tid & 63;
    const int lq = lane >> 4;
    const int ln = lane & 15;
    u16* bufA = smem + w * 6144;
    u16* bufC = bufA + 2048;
    u16* bufB = bufA + 4096;
    const int ebase = blockIdx.x * 64 + w * 16;

    const int e0 = ebase + (lane >> 2);
    const int su = srcI[e0], sd = dstI[e0];

    // ---------- rating path ----------
    f32x4 rh[8];
#pragma unroll
    for (int nt = 0; nt < 8; nt++) rh[nt] = (f32x4){0.f, 0.f, 0.f, 0.f};
    mlp2(urf + (size_t)su * D_, irf + (size_t)sd * D_, lane, lq, ln,
         wbuf + W1R_OFF, wbuf + W2R_OFF, bufA, bufC, bufB, rh);

    // ---------- pr = rh @ wp ----------
    {
        float pp[4][5];
#pragma unroll
        for (int r = 0; r < 4; r++)
#pragma unroll
            for (int c = 0; c < 5; c++) pp[r][c] = 0.f;
#pragma unroll
        for (int nt = 0; nt < 8; nt++) {
            int d = nt * 16 + ln;
            float wpc[5];
#pragma unroll
            for (int c = 0; c < 5; c++) wpc[c] = wp[d * 5 + c];
#pragma unroll
            for (int reg = 0; reg < 4; reg++)
#pragma unroll
                for (int c = 0; c < 5; c++) pp[reg][c] += rh[nt][reg] * wpc[c];
        }
#pragma unroll
        for (int off = 1; off < 16; off <<= 1)
#pragma unroll
            for (int reg = 0; reg < 4; reg++)
#pragma unroll
                for (int c = 0; c < 5; c++)
                    pp[reg][c] += __shfl_xor(pp[reg][c], off, 64);
        if (ln == 0) {
#pragma unroll
            for (int reg = 0; reg < 4; reg++) {
                int e = ebase + lq * 4 + reg;
#pragma unroll
                for (int c = 0; c < 5; c++) out[(size_t)e * 5 + c] = pp[reg][c];
            }
        }
    }

    // ---------- topic path (residual) ----------
    f32x4 th[8];
#pragma unroll
    for (int nt = 0; nt < 8; nt++) th[nt] = rh[nt];
    mlp2(utf + (size_t)su * D_, itf + (size_t)sd * D_, lane, lq, ln,
         wbuf + W1T_OFF, wbuf + W2T_OFF, bufA, bufC, bufB, th);

    // th -> LDS f32 plain layout (16 rows x 128 cols over bufA+bufC = 8 KB)
    float* thb = (float*)bufA;
#pragma unroll
    for (int nt = 0; nt < 8; nt++)
#pragma unroll
        for (int reg = 0; reg < 4; reg++)
            thb[(lq * 4 + reg) * 128 + nt * 16 + ln] = th[nt][reg];
    lds_fence();

    // coalesced bf16 writeout: per row, 64 lanes each pack 2 cols -> 256 B store
#pragma unroll
    for (int m = 0; m < 16; m++) {
        float2 ab = *(const float2*)(thb + m * 128 + lane * 2);
        unsigned pk = (unsigned)f2bf(ab.x) | ((unsigned)f2bf(ab.y) << 16);
        ((unsigned*)(thB + (size_t)(ebase + m) * D_))[lane] = pk;
    }
}

// One edge per 16-lane group; indices shfl-broadcast; fp8 emb gather (8 B/lane).
__global__ __launch_bounds__(256, 8) void review_kernel(
    const u16* __restrict__ thB, const unsigned char* __restrict__ embF8,
    const int* __restrict__ sidI, const int* __restrict__ nsidI,
    float* __restrict__ loss_acc) {
    __shared__ float red[4];
    const int tid = threadIdx.x;
    const int lane = tid & 63;
    const int gl = tid & 15;
    const int e = blockIdx.x * 16 + (tid >> 4);

    int ip = 0, in_ = 0;
    if (gl < L_) { ip = sidI[e * L_ + gl]; in_ = nsidI[e * L_ + gl]; }

    float th8[8];
    {
        union { u16x8 v; unsigned int u[4]; } tu;
        tu.v = *(const u16x8*)(thB + (size_t)e * D_ + gl * 8);
#pragma unroll
        for (int k = 0; k < 4; k++) {
            th8[2 * k]     = bflo(tu.u[k]);
            th8[2 * k + 1] = bfhi(tu.u[k]);
        }
    }

    float ps = 0.f, ns = 0.f;
    float pc = (gl < L_ && ip > 0) ? 1.f : 0.f;
    float nc = (gl < L_ && in_ > 0) ? 1.f : 0.f;

#pragma unroll
    for (int i = 0; i < L_; i++) {
        int s = __shfl(ip, i, 16);
        uint2 cv = *(const uint2*)(embF8 + (size_t)s * D_ + gl * 8);
        int t = __shfl(in_, i, 16);
        uint2 nv = *(const uint2*)(embF8 + (size_t)t * D_ + gl * 8);
#pragma unroll
        for (int j = 0; j < 4; j++) {
            ps = fmaf(th8[j],     fp8dec((cv.x >> (8 * j)) & 0xFFu), ps);
            ps = fmaf(th8[4 + j], fp8dec((cv.y >> (8 * j)) & 0xFFu), ps);
        }
#pragma unroll
        for (int j = 0; j < 4; j++) {
            ns = fmaf(th8[j],     fp8dec((nv.x >> (8 * j)) & 0xFFu), ns);
            ns = fmaf(th8[4 + j], fp8dec((nv.y >> (8 * j)) & 0xFFu), ns);
        }
    }

#pragma unroll
    for (int off = 1; off < 16; off <<= 1) {
        ps += __shfl_xor(ps, off, 64);
        ns += __shfl_xor(ns, off, 64);
        pc += __shfl_xor(pc, off, 64);
        nc += __shfl_xor(nc, off, 64);
    }
    float val = softplus_(ns / (nc + 1e-9f) - ps / (pc + 1e-9f));
    float wl = (gl == 0) ? val : 0.f;
    wl += __shfl_xor(wl, 16, 64);
    wl += __shfl_xor(wl, 32, 64);
    if (lane == 0) red[tid >> 6] = wl;
    __syncthreads();
    if (tid == 0) atomicAdd(loss_acc, red[0] + red[1] + red[2] + red[3]);
}

// ============================================================================
// FALLBACK: fused kernel, pure f32 review path (used only if ws too small)
// ============================================================================
__global__ __launch_bounds__(256, 3) void fused_kernel(
    const float* __restrict__ urf, const float* __restrict__ irf,
    const float* __restrict__ utf, const float* __restrict__ itf,
    const float* __restrict__ wp, const float* __restrict__ emb,
    const int* __restrict__ srcI, const int* __restrict__ dstI,
    const int* __restrict__ sidI, const int* __restrict__ nsidI,
    const u16* __restrict__ wbuf, float* __restrict__ loss_acc,
    float* __restrict__ out) {
    __shared__ u16 smem[4 * 6144];
    const int tid = threadIdx.x;
    const int w = tid >> 6;
    const int lane = tid & 63;
    const int lq = lane >> 4;
    const int ln = lane & 15;
    u16* bufA = smem + w * 6144;
    u16* bufC = bufA + 2048;
    u16* bufB = bufA + 4096;
    const int ebase = blockIdx.x * 64 + w * 16;
    const int e0 = ebase + (lane >> 2);
    const int su = srcI[e0], sd = dstI[e0];

    f32x4 rh[8];
#pragma unroll
    for (int nt = 0; nt < 8; nt++) rh[nt] = (f32x4){0.f, 0.f, 0.f, 0.f};
    mlp2(urf + (size_t)su * D_, irf + (size_t)sd * D_, lane, lq, ln,
         wbuf + W1R_OFF, wbuf + W2R_OFF, bufA, bufC, bufB, rh);

    {
        float pp[4][5];
#pragma unroll
        for (int r = 0; r < 4; r++)
#pragma unroll
            for (int c = 0; c < 5; c++) pp[r][c] = 0.f;
#pragma unroll
        for (int nt = 0; nt < 8; nt++) {
            int d = nt * 16 + ln;
            float wpc[5];
#pragma unroll
            for (int c = 0; c < 5; c++) wpc[c] = wp[d * 5 + c];
#pragma unroll
            for (int reg = 0; reg < 4; reg++)
#pragma unroll
                for (int c = 0; c < 5; c++) pp[reg][c] += rh[nt][reg] * wpc[c];
        }
#pragma unroll
        for (int off = 1; off < 16; off <<= 1)
#pragma unroll
            for (int reg = 0; reg < 4; reg++)
#pragma unroll
                for (int c = 0; c < 5; c++)
                    pp[reg][c] += __shfl_xor(pp[reg][c], off, 64);
        if (ln == 0) {
#pragma unroll
            for (int reg = 0; reg < 4; reg++) {
                int e = ebase + lq * 4 + reg;
#pragma unroll
                for (int c = 0; c < 5; c++) out[(size_t)e * 5 + c] = pp[reg][c];
            }
        }
    }

    f32x4 th[8];
#pragma unroll
    for (int nt = 0; nt < 8; nt++) th[nt] = rh[nt];
    mlp2(utf + (size_t)su * D_, itf + (size_t)sd * D_, lane, lq, ln,
         wbuf + W1T_OFF, wbuf + W2T_OFF, bufA, bufC, bufB, th);

    float* thb = (float*)bufA;
#pragma unroll
    for (int nt = 0; nt < 8; nt++)
#pragma unroll
        for (int reg = 0; reg < 4; reg++)
            thb[(lq * 4 + reg) * 128 + nt * 16 + ln] = th[nt][reg];
    lds_fence();

    float wave_loss = 0.f;
    {
        const int h = lane >> 5, hl = lane & 31;
        for (int mp = 0; mp < 16; mp += 2) {
            int m = mp + h;
            int e = ebase + m;
            float4 t4 = *(const float4*)(thb + m * 128 + hl * 4);
            float ps = 0.f, ns = 0.f;
            int pcnt = 0, ncnt = 0;
#pragma unroll
            for (int i = 0; i < L_; i++) {
                int s = sidI[e * L_ + i];
                pcnt += (s > 0) ? 1 : 0;
                float4 ev = *(const float4*)(emb + (size_t)s * D_ + hl * 4);
                ps += t4.x * ev.x + t4.y * ev.y + t4.z * ev.z + t4.w * ev.w;
            }
#pragma unroll
            for (int i = 0; i < L_; i++) {
                int s = nsidI[e * L_ + i];
                ncnt += (s > 0) ? 1 : 0;
                float4 ev = *(const float4*)(emb + (size_t)s * D_ + hl * 4);
                ns += t4.x * ev.x + t4.y * ev.y + t4.z * ev.z + t4.w * ev.w;
            }
#pragma unroll
            for (int off = 1; off < 32; off <<= 1) {
                ps += __shfl_xor(ps, off, 64);
                ns += __shfl_xor(ns, off, 64);
            }
            if (hl == 0) {
                ps /= ((float)pcnt + 1e-9f);
                ns /= ((float)ncnt + 1e-9f);
                wave_loss += softplus_(ns - ps);
            }
        }
        wave_loss += __shfl_xor(wave_loss, 32, 64);
    }
    if (lane == 0) atomicAdd(loss_acc, wave_loss);
}

__global__ void finish_kernel(const float* __restrict__ loss_acc, float* __restrict__ out) {
    float v = loss_acc[0] * (1.0f / (float)E_);
    out[(size_t)E_ * C_]     = v;
    out[(size_t)E_ * C_ + 1] = v;
}

extern "C" void kernel_launch(void* const* d_in, const int* in_sizes, int n_in,
                              void* d_out, int out_size, void* d_ws, size_t ws_size,
                              hipStream_t stream) {
    const float* urf = (const float*)d_in[0];
    const float* irf = (const float*)d_in[1];
    const float* utf = (const float*)d_in[2];
    const float* itf = (const float*)d_in[3];
    const float* w1r = (const float*)d_in[4];
    const float* w2r = (const float*)d_in[5];
    const float* w1t = (const float*)d_in[6];
    const float* w2t = (const float*)d_in[7];
    const float* wp  = (const float*)d_in[8];
    const float* emb = (const float*)d_in[9];
    const int* srcI  = (const int*)d_in[10];
    const int* dstI  = (const int*)d_in[11];
    const int* sidI  = (const int*)d_in[12];
    const int* nsidI = (const int*)d_in[13];
    float* out = (float*)d_out;

    float* loss_acc = (float*)d_ws;
    u16* wbuf = (u16*)((char*)d_ws + 256);
    unsigned char* embF8 = (unsigned char*)d_ws + EMB_BYTE_OFF;
    u16* thB  = (u16*)((char*)d_ws + TH_BYTE_OFF);

    bool tb = ws_size >= (size_t)TH_BYTE_OFF + TH_BYTES;   // ~76.9 MB

    prep_kernel<<<(WTOT + 255) / 256, 256, 0, stream>>>(w1r, w2r, w1t, w2t, wbuf, loss_acc);

    if (tb) {
        cvt8_kernel<<<(EMB_ELEMS / 8 + 255) / 256, 256, 0, stream>>>(emb, embF8, EMB_ELEMS / 8);
        mlp_kernel<<<E_ / 64, 256, 0, stream>>>(
            urf, irf, utf, itf, wp, srcI, dstI, wbuf, out, thB);
        review_kernel<<<E_ / 16, 256, 0, stream>>>(
            thB, embF8, sidI, nsidI, loss_acc);
    } else {
        fused_kernel<<<E_ / 64, 256, 0, stream>>>(
            urf, irf, utf, itf, wp, emb,
            srcI, dstI, sidI, nsidI, wbuf, loss_acc, out);
    }

    finish_kernel<<<1, 1, 0, stream>>>(loss_acc, out);
}